// Round 11
// baseline (104.651 us; speedup 1.0000x reference)
//
#include <hip/hip_runtime.h>
#include <hip/hip_bf16.h>
#include <stdint.h>

#define N_NODES 100000
#define C 128
#define NET 7
#define E_EDGES 700000
#define S_SLOTS (N_NODES * NET)
#define BM 64
#define NB_CVTX 6250            // 100000*128/8/256
#define NB_CVTW 56              // 7*8*4*64/256
#define NB_INIT ((S_SLOTS + 255) / 256)

typedef __attribute__((ext_vector_type(8))) short short8;
typedef __attribute__((ext_vector_type(4))) float f32x4;
typedef __attribute__((ext_vector_type(4))) unsigned int uint4v;

// ---------- threefry2x32 (JAX), verified round 2 ----------
struct TF2 { uint32_t a, b; };

__host__ __device__ constexpr uint32_t rotl32c(uint32_t v, int r) {
    return (v << r) | (v >> (32 - r));
}

__host__ __device__ constexpr TF2 threefry2x32(uint32_t k0, uint32_t k1,
                                               uint32_t x0, uint32_t x1) {
    const uint32_t ks0 = k0, ks1 = k1, ks2 = 0x1BD11BDAu ^ k0 ^ k1;
    x0 += ks0; x1 += ks1;
#define RND(r) { x0 += x1; x1 = rotl32c(x1, (r)); x1 ^= x0; }
    RND(13) RND(15) RND(26) RND(6)
    x0 += ks1; x1 += ks2 + 1u;
    RND(17) RND(29) RND(16) RND(24)
    x0 += ks2; x1 += ks0 + 2u;
    RND(13) RND(15) RND(26) RND(6)
    x0 += ks0; x1 += ks1 + 3u;
    RND(17) RND(29) RND(16) RND(24)
    x0 += ks1; x1 += ks2 + 4u;
    RND(13) RND(15) RND(26) RND(6)
    x0 += ks2; x1 += ks0 + 5u;
#undef RND
    return TF2{x0, x1};
}

constexpr TF2 K2 = threefry2x32(0u, 42u, 0u, 1u);  // split(key(42),2)[1]

__device__ __forceinline__ uint32_t jax_bits32(uint32_t f) {
    TF2 o = threefry2x32(K2.a, K2.b, 0u, f);
    return o.a ^ o.b;
}

__device__ __forceinline__ unsigned short f2bf(float f) {
    uint32_t u = __float_as_uint(f);
    u += 0x7fffu + ((u >> 16) & 1u);
    return (unsigned short)(u >> 16);
}

// sum two packed-bf16 dwords -> packed bf16 (truncation pack; x0.5 folded into Wf)
__device__ __forceinline__ uint32_t sumpack(uint32_t a, uint32_t b) {
    float alo = __uint_as_float(a << 16);
    float ahi = __uint_as_float(a & 0xffff0000u);
    float blo = __uint_as_float(b << 16);
    float bhi = __uint_as_float(b & 0xffff0000u);
    return (__float_as_uint(ahi + bhi) & 0xffff0000u) | (__float_as_uint(alo + blo) >> 16);
}

__device__ __forceinline__ uint4v sumpack4(uint4v a, uint4v b) {
    uint4v o;
    o.x = sumpack(a.x, b.x); o.y = sumpack(a.y, b.y);
    o.z = sumpack(a.z, b.z); o.w = sumpack(a.w, b.w);
    return o;
}

// ---------- prep1: cvt_x || cvt_w(frag-major, x0.5) || pairs init (self / empty) ----------
__global__ __launch_bounds__(256) void prep1(const float* __restrict__ x,
                                             const float* __restrict__ W,
                                             unsigned short* __restrict__ xb,
                                             unsigned short* __restrict__ Wf,
                                             int2* __restrict__ pairs) {
    const int b = blockIdx.x;
    if (b < NB_CVTX) {
        int i = b * 256 + threadIdx.x;
        const float4* src = (const float4*)x + (size_t)i * 2;
        float4 a = src[0], v = src[1];
        union { unsigned short u[8]; uint4v q; } o;
        o.u[0] = f2bf(a.x); o.u[1] = f2bf(a.y); o.u[2] = f2bf(a.z); o.u[3] = f2bf(a.w);
        o.u[4] = f2bf(v.x); o.u[5] = f2bf(v.y); o.u[6] = f2bf(v.z); o.u[7] = f2bf(v.w);
        ((uint4v*)xb)[i] = o.q;
    } else if (b < NB_CVTX + NB_CVTW) {
        // Wf[((et*8+n16)*4+ks)*512 + lane*8 + j] = 0.5 * W  (frag-major, verified round 4)
        int t = (b - NB_CVTX) * 256 + threadIdx.x;   // < 14336
        int l = t & 63, ks = (t >> 6) & 3, n16 = (t >> 8) & 7, et = t >> 11;
        int n = n16 * 16 + (l & 15);
        int k0 = ks * 32 + (l >> 4) * 8;
        union { unsigned short u[8]; uint4v q; } o;
#pragma unroll
        for (int j = 0; j < 8; j++)
            o.u[j] = f2bf(0.5f * W[(size_t)(et * 128 + k0 + j) * 128 + n]);
        ((uint4v*)Wf)[t] = o.q;
    } else {
        int s = (b - NB_CVTX - NB_CVTW) * 256 + threadIdx.x;
        if (s >= S_SLOTS) return;
        int node = s / NET;
        pairs[s] = (s - node * NET == NET - 1) ? make_int2(node, node)   // self: (x+x)*0.5W
                                               : make_int2(-1, -1);      // empty default
    }
}

// ---------- prep2: run-scan over sorted edges -> sampled pairs ----------
__global__ __launch_bounds__(256) void prep2(const int* __restrict__ idx,
                                             const int* __restrict__ col,
                                             int2* __restrict__ pairs) {
    int e = blockIdx.x * 256 + threadIdx.x;
    if (e >= E_EDGES) return;
    int s = idx[e];
    if (e > 0 && idx[e - 1] == s) return;       // not a run start
    int len = 1;
    while (e + len < E_EDGES && idx[e + len] == s) ++len;
    if (s % NET == NET - 1) return;             // self slot: pre-initialized
    uint32_t b0 = jax_bits32((uint32_t)s * 2u + 0u) & 0x3FFFFFFFu;
    uint32_t b1 = jax_bits32((uint32_t)s * 2u + 1u) & 0x3FFFFFFFu;
    pairs[s] = make_int2(col[e + (int)(b0 % (uint32_t)len)],
                         col[e + (int)(b1 % (uint32_t)len)]);
}

// ---------- fused: 2-wave blocks, wave = 64r x 64c (4x4 frags), quarter-K B pipeline ----------
// Block tile 64x128, 128 thr = 2 waves; wave w: ALL 64 rows x cols w*64..+63.
//   A-LDS dup = 2x (was 8x), B-TA dup = 1x. Operand reads = 8 B/output (floor for 8KB acc).
// Each et (K=128) split into 4 quarters (K=32): B-frags (4 fn x b128) double-buffered in
// regs, ALWAYS issued one quarter before consumption -> each B vmcnt-wait is counted and
// in-order-older than the gather set (issued at q3, consumed at q3 of next et).
// LDS: 2 x [64 rows][256 B]; physical chunk = logical ^ (row&7) both sides (<=2-way, free).
__global__ __launch_bounds__(128) void fused_mfma(const unsigned short* __restrict__ xb,
                                                  const int2* __restrict__ pairs,
                                                  const unsigned short* __restrict__ Wf,
                                                  float* __restrict__ out) {
    __shared__ unsigned char Alds[2][BM * 256];     // 32 KiB
    const int tid  = threadIdx.x;
    const int nb   = blockIdx.x * BM;
    const int w    = tid >> 6, lane = tid & 63;
    const int lr   = lane & 15, lg = lane >> 4;
    const char* xbc = (const char*)xb;

    // staging: thread t owns row t>>1, half h=t&1 (128 B = logical chunks h*8..h*8+7)
    const int r    = tid >> 1, h = tid & 1;
    const int arow = nb + r;
    const int prow = (arow < N_NODES) ? arow * NET : -1;
    const size_t hoff = (size_t)(h * 128);
    const int h8 = h * 8, rx = r & 7, wb = r * 256;

    uint4v g0[8], g1[8];         // one gather set (both sources, 8 chunks)
    short8 bfr[2][4];            // B quarter double-buffer (4 fn frags)

#define GLOAD(PV) { \
    int2 p_ = (PV); \
    if (p_.x >= 0) { \
        const uint4v* s0_ = (const uint4v*)(xbc + ((size_t)p_.x << 8) + hoff); \
        const uint4v* s1_ = (const uint4v*)(xbc + ((size_t)p_.y << 8) + hoff); \
        _Pragma("unroll") \
        for (int c_ = 0; c_ < 8; c_++) { g0[c_] = s0_[c_]; g1[c_] = s1_[c_]; } \
    } else { \
        uint4v z_ = {0u, 0u, 0u, 0u}; \
        _Pragma("unroll") \
        for (int c_ = 0; c_ < 8; c_++) { g0[c_] = z_; g1[c_] = z_; } } }

#define COMBINE(BUF) { \
    _Pragma("unroll") \
    for (int c_ = 0; c_ < 8; c_++) { \
        uint4v v_ = sumpack4(g0[c_], g1[c_]); \
        *(uint4v*)(&Alds[BUF][wb + (((h8 + c_) ^ rx) << 4)]) = v_; } }

// B frags for phase PH = et*4+q: cols w*64 + fn*16, k-window q (frag-major Wf, verified)
#define LOADBQ(DST, PH) { \
    _Pragma("unroll") \
    for (int fn_ = 0; fn_ < 4; fn_++) \
        (DST)[fn_] = *(const short8*)(Wf \
            + (size_t)((((((PH) >> 2) * 8 + w * 4 + fn_) * 4) + ((PH) & 3)) * 512) \
            + lane * 8); }

#define BARRIER() { \
    asm volatile("s_waitcnt lgkmcnt(0)" ::: "memory"); \
    __builtin_amdgcn_s_barrier(); \
    __builtin_amdgcn_sched_barrier(0); }

    f32x4 acc[4][4];
#pragma unroll
    for (int i = 0; i < 4; i++)
#pragma unroll
        for (int j = 0; j < 4; j++) acc[i][j] = (f32x4)0.f;

    int2 pj[7];
#pragma unroll
    for (int j = 0; j < 7; j++)
        pj[j] = (prow >= 0) ? pairs[prow + j] : make_int2(-1, -1);

    // prologue: gathers(et0) -> B(ph0) -> combine(et0) -> gathers(et1)
    GLOAD(pj[0])
    LOADBQ(bfr[0], 0)
    COMBINE(0)               // waits only the (oldest) et0 gathers; B0 stays in flight
    GLOAD(pj[1])
    BARRIER()

#pragma unroll
    for (int et = 0; et < NET; ++et) {
        const int cur = et & 1;
#pragma unroll
        for (int q = 0; q < 4; ++q) {
            const int ph = et * 4 + q;
            // 1) issue next quarter's B (consumed one quarter later; older than any
            //    gather set issued after it -> its wait never drains gathers)
            if (ph + 1 < 4 * NET) LOADBQ(bfr[(q + 1) & 1], ph + 1)
            // 2) at q3: combine(et+1) (consumes gather set, frees regs), then refill
            if (q == 3) {
                if (et + 1 < NET) COMBINE(cur ^ 1)
                if (et + 2 < NET) GLOAD(pj[et + 2])
            }
            // 3) MFMA quarter: 4 ds_read_b128 (A, swizzled) x 4x4 mfma, B from regs
            const int coff = (((q * 4 + lg) ^ (lr & 7)) << 4);
#pragma unroll
            for (int fm = 0; fm < 4; fm++) {
                short8 a_ = *(const short8*)(&Alds[cur][(fm * 16 + lr) * 256 + coff]);
#pragma unroll
                for (int fn = 0; fn < 4; fn++)
                    acc[fm][fn] = __builtin_amdgcn_mfma_f32_16x16x32_bf16(
                        a_, bfr[q & 1][fn], acc[fm][fn], 0, 0, 0);
            }
        }
        // lgkmcnt-only barrier: ds_writes visible; gathers stay in flight
        if (et + 1 < NET) BARRIER()
    }

    // epilogue: D layout col=lane&15, row=(lane>>4)*4+reg (verified)
#pragma unroll
    for (int fm = 0; fm < 4; fm++) {
        int row0 = nb + fm * 16 + lg * 4;
#pragma unroll
        for (int fn = 0; fn < 4; fn++) {
            int colo = w * 64 + fn * 16 + lr;
#pragma unroll
            for (int j = 0; j < 4; j++)
                if (row0 + j < N_NODES)
                    out[(size_t)(row0 + j) * C + colo] = acc[fm][fn][j];
        }
    }
#undef GLOAD
#undef COMBINE
#undef LOADBQ
#undef BARRIER
}

extern "C" void kernel_launch(void* const* d_in, const int* in_sizes, int n_in,
                              void* d_out, int out_size, void* d_ws, size_t ws_size,
                              hipStream_t stream) {
    const float* x   = (const float*)d_in[0];
    const int*   col = (const int*)d_in[1];
    const int*   idx = (const int*)d_in[2];
    const float* W   = (const float*)d_in[3];
    float* out = (float*)d_out;

    int2* pairs        = (int2*)d_ws;                               // 5.6 MB
    unsigned short* xb = (unsigned short*)((char*)pairs + (size_t)S_SLOTS * 8);  // 25.6 MB
    unsigned short* Wf = xb + (size_t)N_NODES * C;                  // 229 KB

    prep1<<<NB_CVTX + NB_CVTW + NB_INIT, 256, 0, stream>>>(x, W, xb, Wf, pairs);
    prep2<<<(E_EDGES + 255) / 256, 256, 0, stream>>>(idx, col, pairs);
    fused_mfma<<<(N_NODES + BM - 1) / BM, 128, 0, stream>>>(xb, pairs, Wf, out);
}